// Round 6
// baseline (4775.374 us; speedup 1.0000x reference)
//
#include <hip/hip_runtime.h>
#include <hip/hip_bf16.h>

#define N_NODES 100000
#define N_EDGES 3200000
#define CH 128
#define NG 128
#define BN_EPS 1e-5f
#define NBUCK 1024    // bucket = dst >> 7 (128 nodes per bucket)
#define EPB 16384     // edges per k_bin block
#define NTILE 7       // src tile = src >> 14 (16384 nodes = 2 MB half-rows)
#define NBLK 1563     // spmm blocks per half: 64 rows each
#define RPB 64        // rows per spmm block
#define LS 68         // lacc row stride (floats), padded vs 64

__device__ __forceinline__ float bflo(unsigned int u) { return __uint_as_float(u << 16); }
__device__ __forceinline__ float bfhi(unsigned int u) { return __uint_as_float(u & 0xffff0000u); }
__device__ __forceinline__ unsigned int f2bf(float f) {  // RNE
    unsigned int u = __float_as_uint(f);
    return (u + 0x7fffu + ((u >> 16) & 1u)) >> 16;
}
__device__ __forceinline__ unsigned int pack2bf(float x, float y) {
    return f2bf(x) | (f2bf(y) << 16);
}

// ---------------- bucket histogram ----------------
__global__ __launch_bounds__(256) void k_bhist(const int* __restrict__ dst, int* __restrict__ bcnt) {
    __shared__ int lh[NBUCK];
    for (int i = threadIdx.x; i < NBUCK; i += 256) lh[i] = 0;
    __syncthreads();
    for (int e = blockIdx.x * 256 + threadIdx.x; e < N_EDGES; e += gridDim.x * 256)
        atomicAdd(&lh[dst[e] >> 7], 1);
    __syncthreads();
    for (int i = threadIdx.x; i < NBUCK; i += 256) {
        int v = lh[i];
        if (v) atomicAdd(&bcnt[i], v);
    }
}

// ---------------- bucket scan: bcnt[1024] -> boffs, bcur ----------------
__global__ __launch_bounds__(256) void k_bscan(const int* __restrict__ bcnt, int* __restrict__ boffs,
                                               int* __restrict__ bcur) {
    __shared__ int sm[256];
    int t = threadIdx.x;
    int4 v = *(const int4*)&bcnt[t * 4];
    int tsum = v.x + v.y + v.z + v.w;
    sm[t] = tsum;
    __syncthreads();
    for (int off = 1; off < 256; off <<= 1) {
        int val = sm[t];
        int add = (t >= off) ? sm[t - off] : 0;
        __syncthreads();
        sm[t] = val + add;
        __syncthreads();
    }
    int excl = sm[t] - tsum;
    int o0 = excl, o1 = excl + v.x, o2 = o1 + v.y, o3 = o2 + v.z;
    boffs[t * 4] = o0; boffs[t * 4 + 1] = o1; boffs[t * 4 + 2] = o2; boffs[t * 4 + 3] = o3;
    bcur[t * 4] = o0;  bcur[t * 4 + 1] = o1;  bcur[t * 4 + 2] = o2;  bcur[t * 4 + 3] = o3;
}

// ---------------- bin edges into per-bucket packed segments (two-pass per block) ----------------
// packed entry: (src << 7) | (dst & 127)
__global__ __launch_bounds__(256) void k_bin(const int* __restrict__ src, const int* __restrict__ dst,
                                             int* __restrict__ bcur, unsigned int* __restrict__ pairs) {
    __shared__ int lhist[NBUCK];
    __shared__ int lbase[NBUCK];
    int t = threadIdx.x;
    for (int i = t; i < NBUCK; i += 256) lhist[i] = 0;
    __syncthreads();
    int base = blockIdx.x * EPB;
    int lim = min(base + EPB, N_EDGES);
    for (int e = base + t; e < lim; e += 256)
        atomicAdd(&lhist[dst[e] >> 7], 1);
    __syncthreads();
    for (int i = t; i < NBUCK; i += 256) {
        int h = lhist[i];
        lbase[i] = h ? atomicAdd(&bcur[i], h) : 0;
        lhist[i] = 0;
    }
    __syncthreads();
    for (int e = base + t; e < lim; e += 256) {
        int d = dst[e];
        int b = d >> 7;
        int r = atomicAdd(&lhist[b], 1);
        pairs[lbase[b] + r] = ((unsigned int)src[e] << 7) | ((unsigned int)d & 127u);
    }
}

// ---------------- pass A: per-(bucket,tile) counts + dinv ----------------
__global__ __launch_bounds__(256) void k_bfillA(const unsigned int* __restrict__ pairs,
                                                const int* __restrict__ boffs,
                                                int* __restrict__ tcnt, float* __restrict__ dinv) {
    __shared__ int cnt[128 * NTILE];
    int b = blockIdx.x, t = threadIdx.x;
    for (int i = t; i < 128 * NTILE; i += 256) cnt[i] = 0;
    __syncthreads();
    int p0 = boffs[b];
    int p1 = (b == NBUCK - 1) ? N_EDGES : boffs[b + 1];
    for (int p = p0 + t; p < p1; p += 256) {
        unsigned int e = pairs[p];
        int local = (int)(e & 127u);
        int tile = (int)((e >> 7) >> 14);
        atomicAdd(&cnt[local * NTILE + tile], 1);
    }
    __syncthreads();
    if (t < 128) {
        int dsum = 0;
        #pragma unroll
        for (int k = 0; k < NTILE; ++k) dsum += cnt[t * NTILE + k];
        int node = (b << 7) + t;
        if (node < N_NODES) dinv[node] = rsqrtf((float)(dsum + 1));
    }
    if (t < NTILE) {
        int s = 0;
        for (int l = 0; l < 128; ++l) s += cnt[l * NTILE + t];
        tcnt[t * NBUCK + b] = s;
    }
}

// ---------------- scan 7168 per-(tile,bucket) counts -> tbase ----------------
__global__ __launch_bounds__(256) void k_tscan(const int* __restrict__ tcnt, int* __restrict__ tbase) {
    __shared__ int sm[256];
    int t = threadIdx.x;
    int base = t * 28;  // 7168 = 256*28
    int s = 0;
    for (int i = 0; i < 28; ++i) s += tcnt[base + i];
    sm[t] = s;
    __syncthreads();
    for (int off = 1; off < 256; off <<= 1) {
        int val = sm[t];
        int add = (t >= off) ? sm[t - off] : 0;
        __syncthreads();
        sm[t] = val + add;
        __syncthreads();
    }
    int run = sm[t] - s;
    for (int i = 0; i < 28; ++i) {
        int v = tcnt[base + i];
        tbase[base + i] = run;
        run += v;
    }
}

// ---------------- pass B: tile-major perm fill + BS block starts ----------------
// perm entry: (src << 6) | (node & 63)
__global__ __launch_bounds__(256) void k_bfillB(const unsigned int* __restrict__ pairs,
                                                const int* __restrict__ boffs,
                                                const int* __restrict__ tbase,
                                                int* __restrict__ BS, unsigned int* __restrict__ perm) {
    __shared__ int cnt[128 * NTILE];
    __shared__ int pos[128 * NTILE];
    int b = blockIdx.x, t = threadIdx.x;
    for (int i = t; i < 128 * NTILE; i += 256) cnt[i] = 0;
    __syncthreads();
    int p0 = boffs[b];
    int p1 = (b == NBUCK - 1) ? N_EDGES : boffs[b + 1];
    for (int p = p0 + t; p < p1; p += 256) {
        unsigned int e = pairs[p];
        int local = (int)(e & 127u);
        int tile = (int)((e >> 7) >> 14);
        atomicAdd(&cnt[local * NTILE + tile], 1);
    }
    __syncthreads();
    if (t < NTILE) {
        int run = tbase[t * NBUCK + b];
        int blk0 = b * 2;
        if (blk0 < NBLK + 1) BS[t * (NBLK + 1) + blk0] = run;
        for (int l = 0; l < 128; ++l) {
            if (l == 64 && blk0 + 1 < NBLK + 1) BS[t * (NBLK + 1) + blk0 + 1] = run;
            pos[l * NTILE + t] = run;
            run += cnt[l * NTILE + t];
        }
    }
    __syncthreads();
    for (int i = t; i < 128 * NTILE; i += 256) cnt[i] = 0;
    __syncthreads();
    for (int p = p0 + t; p < p1; p += 256) {
        unsigned int e = pairs[p];
        int local = (int)(e & 127u);
        unsigned int s = e >> 7;
        int tile = (int)(s >> 14);
        int r = atomicAdd(&cnt[local * NTILE + tile], 1);
        perm[pos[local * NTILE + tile] + r] = (s << 6) | ((unsigned int)local & 63u);
    }
}

// ---------------- GEMM: Y_bf16[nrows,128] = X[nrows,128] @ W[128,128] ----------------
template <int BF16IN>
__global__ __launch_bounds__(256) void k_gemm(const void* __restrict__ Xv, const float* __restrict__ W,
                                              unsigned int* __restrict__ Yb, int nrows) {
    __shared__ float xsT[128 * 64];  // [k][r]
    int row0 = blockIdx.x * 64;
    int t = threadIdx.x;
    {
        int r = t >> 2, q = t & 3;
        int grow = row0 + r;
        bool ok = grow < nrows;
        if (BF16IN) {
            const uint2* srcp = (const uint2*)((const unsigned int*)Xv + (size_t)grow * 64 + q * 16);
            #pragma unroll
            for (int i = 0; i < 8; ++i) {
                uint2 u = ok ? srcp[i] : make_uint2(0, 0);
                int c = q * 32 + i * 4;
                xsT[(c + 0) * 64 + r] = bflo(u.x);
                xsT[(c + 1) * 64 + r] = bfhi(u.x);
                xsT[(c + 2) * 64 + r] = bflo(u.y);
                xsT[(c + 3) * 64 + r] = bfhi(u.y);
            }
        } else {
            const float4* srcp = (const float4*)((const float*)Xv + (size_t)grow * CH + q * 32);
            #pragma unroll
            for (int i = 0; i < 8; ++i) {
                float4 v = ok ? srcp[i] : make_float4(0.f, 0.f, 0.f, 0.f);
                int c = q * 32 + i * 4;
                xsT[(c + 0) * 64 + r] = v.x;
                xsT[(c + 1) * 64 + r] = v.y;
                xsT[(c + 2) * 64 + r] = v.z;
                xsT[(c + 3) * 64 + r] = v.w;
            }
        }
    }
    __syncthreads();
    int tx = t & 15, ty = t >> 4;
    float acc[4][8];
    #pragma unroll
    for (int i = 0; i < 4; ++i)
        #pragma unroll
        for (int j = 0; j < 8; ++j) acc[i][j] = 0.f;

    const float4* xs4 = (const float4*)xsT;
    #pragma unroll 4
    for (int k = 0; k < 128; ++k) {
        float4 a = xs4[k * 16 + ty];
        float4 w0 = *(const float4*)&W[k * CH + tx * 8];
        float4 w1 = *(const float4*)&W[k * CH + tx * 8 + 4];
        float av[4] = {a.x, a.y, a.z, a.w};
        float wv[8] = {w0.x, w0.y, w0.z, w0.w, w1.x, w1.y, w1.z, w1.w};
        #pragma unroll
        for (int i = 0; i < 4; ++i)
            #pragma unroll
            for (int j = 0; j < 8; ++j) acc[i][j] += av[i] * wv[j];
    }
    #pragma unroll
    for (int i = 0; i < 4; ++i) {
        int grow = row0 + ty * 4 + i;
        if (grow < nrows) {
            unsigned int o[4];
            #pragma unroll
            for (int j = 0; j < 4; ++j) o[j] = pack2bf(acc[i][2 * j], acc[i][2 * j + 1]);
            *(uint4*)&Yb[(size_t)grow * 64 + tx * 4] = *(uint4*)o;
        }
    }
}

// ---------------- SpMM tile-swept gather core (shared by both layers) ----------------
// grid 2*NBLK blocks; half = channel half; block owns rows [bid*64, bid*64+64)
#define SPMM_PROLOG_GATHER()                                                           \
    int hf = (blockIdx.x >= NBLK) ? 1 : 0;                                             \
    int bid = blockIdx.x - hf * NBLK;                                                  \
    int row0 = bid * RPB;                                                              \
    int tid = threadIdx.x;                                                             \
    for (int i = tid; i < RPB * LS; i += 256) lacc[i] = 0.f;                           \
    if (tid < RPB) {                                                                   \
        int node = row0 + tid;                                                         \
        ldin[tid] = (node < N_NODES) ? dinv[node] : 0.f;                               \
    }                                                                                  \
    __syncthreads();                                                                   \
    {                                                                                  \
        int slot = tid >> 4, c = tid & 15;                                             \
        const uint2* xw2 = (const uint2*)xw;                                           \
        for (int t = 0; t < NTILE; ++t) {                                              \
            int j0 = BS[t * (NBLK + 1) + bid];                                         \
            int j1 = BS[t * (NBLK + 1) + bid + 1];                                     \
            for (int j = j0 + slot; j < j1; j += 16) {                                 \
                unsigned int e = perm[j];                                              \
                int s = (int)(e >> 6), l = (int)(e & 63u);                             \
                float f = dinv[s] * ldin[l];                                           \
                uint2 v = xw2[(size_t)s * 32 + hf * 16 + c];                           \
                float* a = &lacc[l * LS + c * 4];                                      \
                atomicAdd(&a[0], f * bflo(v.x));                                       \
                atomicAdd(&a[1], f * bfhi(v.x));                                       \
                atomicAdd(&a[2], f * bflo(v.y));                                       \
                atomicAdd(&a[3], f * bfhi(v.y));                                       \
            }                                                                          \
        }                                                                              \
    }                                                                                  \
    __syncthreads();

// ---------------- SpMM layer 1: + self-loop + bias + BN + ReLU -> bf16 ----------------
__global__ __launch_bounds__(256) void k_spmm1(
    const unsigned int* __restrict__ xw, const unsigned int* __restrict__ perm,
    const int* __restrict__ BS, const float* __restrict__ dinv, const float* __restrict__ bias,
    const float* __restrict__ gamma, const float* __restrict__ beta,
    const float* __restrict__ rmean, const float* __restrict__ rvar, unsigned int* __restrict__ outb) {
    __shared__ float lacc[RPB * LS];
    __shared__ float ldin[RPB];
    SPMM_PROLOG_GATHER()
    #pragma unroll
    for (int it = 0; it < 8; ++it) {
        int r = (tid >> 5) + it * 8;
        int node = row0 + r;
        if (node < N_NODES) {
            int cp = tid & 31;
            int ch = hf * 64 + cp * 2;
            float di = ldin[r];
            unsigned int sv = xw[(size_t)node * 64 + hf * 32 + cp];
            float ax = lacc[r * LS + cp * 2]     + di * di * bflo(sv);
            float ay = lacc[r * LS + cp * 2 + 1] + di * di * bfhi(sv);
            float2 bb = *(const float2*)&bias[ch];
            float2 gg = *(const float2*)&gamma[ch];
            float2 be = *(const float2*)&beta[ch];
            float2 rm = *(const float2*)&rmean[ch];
            float2 rv = *(const float2*)&rvar[ch];
            float vx = fmaxf((ax + bb.x - rm.x) * (gg.x * rsqrtf(rv.x + BN_EPS)) + be.x, 0.f);
            float vy = fmaxf((ay + bb.y - rm.y) * (gg.y * rsqrtf(rv.y + BN_EPS)) + be.y, 0.f);
            outb[(size_t)node * 64 + hf * 32 + cp] = pack2bf(vx, vy);
        }
    }
}

// ---------------- SpMM layer 2: + self-loop + bias + pooled segment flush ----------------
__global__ __launch_bounds__(256) void k_spmm2(
    const unsigned int* __restrict__ xw, const unsigned int* __restrict__ perm,
    const int* __restrict__ BS, const float* __restrict__ dinv, const float* __restrict__ bias,
    const int* __restrict__ batch, float* __restrict__ psum, int* __restrict__ pcnt) {
    __shared__ float lacc[RPB * LS];
    __shared__ float ldin[RPB];
    SPMM_PROLOG_GATHER()
    #pragma unroll
    for (int it = 0; it < 8; ++it) {
        int r = (tid >> 5) + it * 8;
        int node = row0 + r;
        if (node < N_NODES) {
            int cp = tid & 31;
            int ch = hf * 64 + cp * 2;
            float di = ldin[r];
            unsigned int sv = xw[(size_t)node * 64 + hf * 32 + cp];
            lacc[r * LS + cp * 2]     += di * di * bflo(sv) + bias[ch];
            lacc[r * LS + cp * 2 + 1] += di * di * bfhi(sv) + bias[ch + 1];
        }
    }
    __syncthreads();
    if (tid < 64) {
        float run = 0.f;
        int gprev = -1, cnt = 0;
        for (int r = 0; r < RPB; ++r) {
            int node = row0 + r;
            if (node >= N_NODES) break;
            int gb = batch[node];
            if (gb != gprev) {
                if (gprev >= 0) {
                    unsafeAtomicAdd(&psum[gprev * CH + hf * 64 + tid], run);
                    if (tid == 0 && hf == 0) atomicAdd(&pcnt[gprev], cnt);
                }
                gprev = gb; run = 0.f; cnt = 0;
            }
            run += lacc[r * LS + tid];
            cnt++;
        }
        if (gprev >= 0) {
            unsafeAtomicAdd(&psum[gprev * CH + hf * 64 + tid], run);
            if (tid == 0 && hf == 0) atomicAdd(&pcnt[gprev], cnt);
        }
    }
}

// ---------------- head: pooled mean -> FC(relu) -> classifier ----------------
__global__ __launch_bounds__(128) void k_head(const float* __restrict__ psum, const int* __restrict__ pcnt,
                                              const float* __restrict__ fw1, const float* __restrict__ fb1,
                                              const float* __restrict__ cw, const float* __restrict__ cb,
                                              float* __restrict__ out) {
    __shared__ float fws[128 * 64];
    for (int i = threadIdx.x; i < 128 * 64; i += 128) fws[i] = fw1[i];
    __syncthreads();
    int g = threadIdx.x;
    float z[64];
    #pragma unroll
    for (int j = 0; j < 64; ++j) z[j] = fb1[j];
    float cnt = fmaxf((float)pcnt[g], 1.f);
    float inv = 1.f / cnt;
    for (int c = 0; c < 128; ++c) {
        float p = psum[g * CH + c] * inv;
        #pragma unroll
        for (int j = 0; j < 64; ++j) z[j] += p * fws[c * 64 + j];
    }
    float o0 = cb[0], o1 = cb[1];
    #pragma unroll
    for (int j = 0; j < 64; ++j) {
        float zz = fmaxf(z[j], 0.f);
        o0 += zz * cw[j * 2];
        o1 += zz * cw[j * 2 + 1];
    }
    out[g * 2] = o0;
    out[g * 2 + 1] = o1;
}

extern "C" void kernel_launch(void* const* d_in, const int* in_sizes, int n_in,
                              void* d_out, int out_size, void* d_ws, size_t ws_size,
                              hipStream_t stream) {
    const float* x     = (const float*)d_in[0];
    const int*   ei    = (const int*)d_in[1];
    const int*   batch = (const int*)d_in[2];
    const float* W1    = (const float*)d_in[3];
    const float* b1    = (const float*)d_in[4];
    const float* gamma = (const float*)d_in[5];
    const float* beta  = (const float*)d_in[6];
    const float* rmean = (const float*)d_in[7];
    const float* rvar  = (const float*)d_in[8];
    const float* W2    = (const float*)d_in[9];
    const float* b2    = (const float*)d_in[10];
    const float* fw1   = (const float*)d_in[11];
    const float* fb1   = (const float*)d_in[12];
    const float* cw    = (const float*)d_in[13];
    const float* cb    = (const float*)d_in[14];
    const int* srcp = ei;
    const int* dstp = ei + N_EDGES;

    char* w = (char*)d_ws;
    // zeroed region
    int*   bcnt  = (int*)w;   w += 4096;
    float* psum  = (float*)w; w += 65536;
    int*   pcnt  = (int*)w;   w += 512;
    size_t zbytes = 4096 + 65536 + 512;
    // non-zeroed
    int*   boffs = (int*)w;   w += 4096;
    int*   bcur  = (int*)w;   w += 4096;
    int*   tcnt  = (int*)w;   w += 28672;
    int*   tbase = (int*)w;   w += 28672;
    int*   BS    = (int*)w;   w += 43792;   // 7 * 1564 ints
    float* dinv  = (float*)w; w += 400000;
    unsigned int* pairs = (unsigned int*)w; w += 12800000;
    unsigned int* perm  = (unsigned int*)w; w += 12800000;
    unsigned int* bufA  = (unsigned int*)w; w += 25600000;  // bf16x2 [100k,64]
    unsigned int* bufB  = (unsigned int*)w; w += 25600000;  // bf16x2 [100k,64]

    hipMemsetAsync(d_ws, 0, zbytes, stream);
    k_bhist<<<200, 256, 0, stream>>>(dstp, bcnt);
    k_bscan<<<1, 256, 0, stream>>>(bcnt, boffs, bcur);
    k_bin<<<(N_EDGES + EPB - 1) / EPB, 256, 0, stream>>>(srcp, dstp, bcur, pairs);
    k_bfillA<<<NBUCK, 256, 0, stream>>>(pairs, boffs, tcnt, dinv);
    k_tscan<<<1, 256, 0, stream>>>(tcnt, tbase);
    k_bfillB<<<NBUCK, 256, 0, stream>>>(pairs, boffs, tbase, BS, perm);
    k_gemm<0><<<1563, 256, 0, stream>>>(x, W1, bufA, N_NODES);
    k_spmm1<<<2 * NBLK, 256, 0, stream>>>(bufA, perm, BS, dinv, b1, gamma, beta, rmean, rvar, bufB);
    k_gemm<1><<<1563, 256, 0, stream>>>(bufB, W2, bufA, N_NODES);
    k_spmm2<<<2 * NBLK, 256, 0, stream>>>(bufA, perm, BS, dinv, b2, batch, psum, pcnt);
    k_head<<<1, 128, 0, stream>>>(psum, pcnt, fw1, fb1, cw, cb, (float*)d_out);
}

// Round 7
// 687.463 us; speedup vs baseline: 6.9464x; 6.9464x over previous
//
#include <hip/hip_runtime.h>
#include <hip/hip_bf16.h>

#define N_NODES 100000
#define N_EDGES 3200000
#define CH 128
#define NG 128
#define BN_EPS 1e-5f
#define NBUCK 1024   // bucket = dst >> 7 (128 nodes per bucket)
#define EPB 16384    // edges per k_bin block
#define NTILE 7      // src tile = src >> 14 (16384 nodes ~ 2 MB of rows)

__device__ __forceinline__ float bflo(unsigned int u) { return __uint_as_float(u << 16); }
__device__ __forceinline__ float bfhi(unsigned int u) { return __uint_as_float(u & 0xffff0000u); }
__device__ __forceinline__ unsigned int f2bf(float f) {  // RNE
    unsigned int u = __float_as_uint(f);
    return (u + 0x7fffu + ((u >> 16) & 1u)) >> 16;
}
__device__ __forceinline__ unsigned int pack2bf(float x, float y) {
    return f2bf(x) | (f2bf(y) << 16);
}

// ---------------- bucket histogram ----------------
__global__ __launch_bounds__(256) void k_bhist(const int* __restrict__ dst, int* __restrict__ bcnt) {
    __shared__ int lh[NBUCK];
    for (int i = threadIdx.x; i < NBUCK; i += 256) lh[i] = 0;
    __syncthreads();
    for (int e = blockIdx.x * 256 + threadIdx.x; e < N_EDGES; e += gridDim.x * 256)
        atomicAdd(&lh[dst[e] >> 7], 1);
    __syncthreads();
    for (int i = threadIdx.x; i < NBUCK; i += 256) {
        int v = lh[i];
        if (v) atomicAdd(&bcnt[i], v);
    }
}

// ---------------- bucket scan: bcnt[1024] -> boffs, bcur ----------------
__global__ __launch_bounds__(256) void k_bscan(const int* __restrict__ bcnt, int* __restrict__ boffs,
                                               int* __restrict__ bcur) {
    __shared__ int sm[256];
    int t = threadIdx.x;
    int4 v = *(const int4*)&bcnt[t * 4];
    int tsum = v.x + v.y + v.z + v.w;
    sm[t] = tsum;
    __syncthreads();
    for (int off = 1; off < 256; off <<= 1) {
        int val = sm[t];
        int add = (t >= off) ? sm[t - off] : 0;
        __syncthreads();
        sm[t] = val + add;
        __syncthreads();
    }
    int excl = sm[t] - tsum;
    int o0 = excl, o1 = excl + v.x, o2 = o1 + v.y, o3 = o2 + v.z;
    boffs[t * 4] = o0; boffs[t * 4 + 1] = o1; boffs[t * 4 + 2] = o2; boffs[t * 4 + 3] = o3;
    bcur[t * 4] = o0;  bcur[t * 4 + 1] = o1;  bcur[t * 4 + 2] = o2;  bcur[t * 4 + 3] = o3;
}

// ---------------- bin edges into per-bucket packed segments (two-pass per block) ----------------
// packed entry: (src << 7) | (dst & 127)
__global__ __launch_bounds__(256) void k_bin(const int* __restrict__ src, const int* __restrict__ dst,
                                             int* __restrict__ bcur, unsigned int* __restrict__ pairs) {
    __shared__ int lhist[NBUCK];
    __shared__ int lbase[NBUCK];
    int t = threadIdx.x;
    for (int i = t; i < NBUCK; i += 256) lhist[i] = 0;
    __syncthreads();
    int base = blockIdx.x * EPB;
    int lim = min(base + EPB, N_EDGES);
    for (int e = base + t; e < lim; e += 256)
        atomicAdd(&lhist[dst[e] >> 7], 1);
    __syncthreads();
    for (int i = t; i < NBUCK; i += 256) {
        int h = lhist[i];
        lbase[i] = h ? atomicAdd(&bcur[i], h) : 0;
        lhist[i] = 0;
    }
    __syncthreads();
    for (int e = base + t; e < lim; e += 256) {
        int d = dst[e];
        int b = d >> 7;
        int r = atomicAdd(&lhist[b], 1);
        pairs[lbase[b] + r] = ((unsigned int)src[e] << 7) | ((unsigned int)d & 127u);
    }
}

// ---------------- per-bucket CSR fill, edges tile-sorted within each row ----------------
__global__ __launch_bounds__(256) void k_bfill(const unsigned int* __restrict__ pairs,
                                               const int* __restrict__ boffs,
                                               int* __restrict__ offs, int* __restrict__ deg,
                                               float* __restrict__ dinv, int* __restrict__ perm) {
    __shared__ int cnt[128 * 8];  // [local][tile], stride 8
    __shared__ int pos[128 * 8];
    __shared__ int lsc[128];
    int b = blockIdx.x, t = threadIdx.x;
    for (int i = t; i < 128 * 8; i += 256) cnt[i] = 0;
    __syncthreads();
    int p0 = boffs[b];
    int p1 = (b == NBUCK - 1) ? N_EDGES : boffs[b + 1];
    // pass 1: per-(row,tile) counts
    for (int p = p0 + t; p < p1; p += 256) {
        unsigned int e = pairs[p];
        int local = (int)(e & 127u);
        int tile = (int)((e >> 7) >> 14);
        atomicAdd(&cnt[local * 8 + tile], 1);
    }
    __syncthreads();
    int mydeg = 0;
    if (t < 128) {
        #pragma unroll
        for (int k = 0; k < NTILE; ++k) mydeg += cnt[t * 8 + k];
        lsc[t] = mydeg;
    }
    __syncthreads();
    // Hillis-Steele inclusive scan over 128 row degrees
    for (int off = 1; off < 128; off <<= 1) {
        int val = 0, add = 0;
        if (t < 128) { val = lsc[t]; add = (t >= off) ? lsc[t - off] : 0; }
        __syncthreads();
        if (t < 128) lsc[t] = val + add;
        __syncthreads();
    }
    if (t < 128) {
        int excl = lsc[t] - mydeg + p0;
        int node = (b << 7) + t;
        if (node < N_NODES) {
            offs[node] = excl;
            deg[node] = mydeg;
            dinv[node] = rsqrtf((float)(mydeg + 1));
        }
        int run = excl;
        #pragma unroll
        for (int k = 0; k < NTILE; ++k) {
            pos[t * 8 + k] = run;
            run += cnt[t * 8 + k];
            cnt[t * 8 + k] = 0;
        }
    }
    __syncthreads();
    // pass 2: place edges tile-major within each row (soft L2 tiling for spmm)
    for (int p = p0 + t; p < p1; p += 256) {
        unsigned int e = pairs[p];
        int local = (int)(e & 127u);
        unsigned int s = e >> 7;
        int tile = (int)(s >> 14);
        int r = atomicAdd(&cnt[local * 8 + tile], 1);
        perm[pos[local * 8 + tile] + r] = (int)s;
    }
}

// ---------------- GEMM: Y_bf16[nrows,128] = X[nrows,128] @ W[128,128] ----------------
template <int BF16IN>
__global__ __launch_bounds__(256) void k_gemm(const void* __restrict__ Xv, const float* __restrict__ W,
                                              unsigned int* __restrict__ Yb, int nrows) {
    __shared__ float xsT[128 * 64];  // [k][r]
    int row0 = blockIdx.x * 64;
    int t = threadIdx.x;
    {
        int r = t >> 2, q = t & 3;
        int grow = row0 + r;
        bool ok = grow < nrows;
        if (BF16IN) {
            const uint2* srcp = (const uint2*)((const unsigned int*)Xv + (size_t)grow * 64 + q * 16);
            #pragma unroll
            for (int i = 0; i < 8; ++i) {
                uint2 u = ok ? srcp[i] : make_uint2(0, 0);
                int c = q * 32 + i * 4;
                xsT[(c + 0) * 64 + r] = bflo(u.x);
                xsT[(c + 1) * 64 + r] = bfhi(u.x);
                xsT[(c + 2) * 64 + r] = bflo(u.y);
                xsT[(c + 3) * 64 + r] = bfhi(u.y);
            }
        } else {
            const float4* srcp = (const float4*)((const float*)Xv + (size_t)grow * CH + q * 32);
            #pragma unroll
            for (int i = 0; i < 8; ++i) {
                float4 v = ok ? srcp[i] : make_float4(0.f, 0.f, 0.f, 0.f);
                int c = q * 32 + i * 4;
                xsT[(c + 0) * 64 + r] = v.x;
                xsT[(c + 1) * 64 + r] = v.y;
                xsT[(c + 2) * 64 + r] = v.z;
                xsT[(c + 3) * 64 + r] = v.w;
            }
        }
    }
    __syncthreads();
    int tx = t & 15, ty = t >> 4;
    float acc[4][8];
    #pragma unroll
    for (int i = 0; i < 4; ++i)
        #pragma unroll
        for (int j = 0; j < 8; ++j) acc[i][j] = 0.f;

    const float4* xs4 = (const float4*)xsT;
    #pragma unroll 4
    for (int k = 0; k < 128; ++k) {
        float4 a = xs4[k * 16 + ty];
        float4 w0 = *(const float4*)&W[k * CH + tx * 8];
        float4 w1 = *(const float4*)&W[k * CH + tx * 8 + 4];
        float av[4] = {a.x, a.y, a.z, a.w};
        float wv[8] = {w0.x, w0.y, w0.z, w0.w, w1.x, w1.y, w1.z, w1.w};
        #pragma unroll
        for (int i = 0; i < 4; ++i)
            #pragma unroll
            for (int j = 0; j < 8; ++j) acc[i][j] += av[i] * wv[j];
    }
    #pragma unroll
    for (int i = 0; i < 4; ++i) {
        int grow = row0 + ty * 4 + i;
        if (grow < nrows) {
            unsigned int o[4];
            #pragma unroll
            for (int j = 0; j < 4; ++j) o[j] = pack2bf(acc[i][2 * j], acc[i][2 * j + 1]);
            *(uint4*)&Yb[(size_t)grow * 64 + tx * 4] = *(uint4*)o;
        }
    }
}

// ---------------- SpMM gather core: 4 edge-slots x 16 lanes, 4x unrolled uint4 loads ----------------
#define ACC8(f, v)                                                                     \
    acc[0] += f * bflo(v.x); acc[1] += f * bfhi(v.x);                                  \
    acc[2] += f * bflo(v.y); acc[3] += f * bfhi(v.y);                                  \
    acc[4] += f * bflo(v.z); acc[5] += f * bfhi(v.z);                                  \
    acc[6] += f * bflo(v.w); acc[7] += f * bfhi(v.w);

#define SPMM_GATHER()                                                                  \
    int w = threadIdx.x >> 6;                                                          \
    int row = __builtin_amdgcn_readfirstlane(blockIdx.x * 4 + w);                      \
    int lane = threadIdx.x & 63;                                                       \
    int g = lane >> 4, c = lane & 15;                                                  \
    float di = dinv[row];                                                              \
    float acc[8];                                                                      \
    _Pragma("unroll") for (int i = 0; i < 8; ++i) acc[i] = 0.f;                        \
    int beg = offs[row], end = beg + deg[row];                                         \
    int j = beg + g;                                                                   \
    for (; j + 12 < end; j += 16) {                                                    \
        int s0 = perm[j], s1 = perm[j + 4], s2 = perm[j + 8], s3 = perm[j + 12];       \
        float f0 = dinv[s0], f1 = dinv[s1], f2 = dinv[s2], f3 = dinv[s3];              \
        uint4 v0 = xw4[(size_t)s0 * 16 + c];                                           \
        uint4 v1 = xw4[(size_t)s1 * 16 + c];                                           \
        uint4 v2 = xw4[(size_t)s2 * 16 + c];                                           \
        uint4 v3 = xw4[(size_t)s3 * 16 + c];                                           \
        f0 *= di; f1 *= di; f2 *= di; f3 *= di;                                        \
        ACC8(f0, v0) ACC8(f1, v1) ACC8(f2, v2) ACC8(f3, v3)                            \
    }                                                                                  \
    for (; j + 4 < end; j += 8) {                                                      \
        int s0 = perm[j], s1 = perm[j + 4];                                            \
        float f0 = di * dinv[s0], f1 = di * dinv[s1];                                  \
        uint4 v0 = xw4[(size_t)s0 * 16 + c];                                           \
        uint4 v1 = xw4[(size_t)s1 * 16 + c];                                           \
        ACC8(f0, v0) ACC8(f1, v1)                                                      \
    }                                                                                  \
    if (j < end) {                                                                     \
        int s = perm[j];                                                               \
        float f = di * dinv[s];                                                        \
        uint4 v = xw4[(size_t)s * 16 + c];                                             \
        ACC8(f, v)                                                                     \
    }                                                                                  \
    _Pragma("unroll") for (int i = 0; i < 8; ++i) {                                    \
        acc[i] += __shfl_xor(acc[i], 16, 64);                                          \
        acc[i] += __shfl_xor(acc[i], 32, 64);                                          \
    }

// ---------------- SpMM layer 1: aggregate + bias + BN + ReLU -> bf16 ----------------
__global__ __launch_bounds__(256) void k_spmm_bn_relu(
    const uint4* __restrict__ xw4, const int* __restrict__ perm, const int* __restrict__ offs,
    const int* __restrict__ deg, const float* __restrict__ dinv, const float* __restrict__ bias,
    const float* __restrict__ gamma, const float* __restrict__ beta,
    const float* __restrict__ rmean, const float* __restrict__ rvar, uint4* __restrict__ outb) {
    SPMM_GATHER()
    if (g == 0) {
        uint4 v = xw4[(size_t)row * 16 + c];
        float sd = di * di;
        ACC8(sd, v)
        int ch = c * 8;
        float r[8];
        #pragma unroll
        for (int i = 0; i < 8; ++i) {
            float sc = gamma[ch + i] * rsqrtf(rvar[ch + i] + BN_EPS);
            r[i] = fmaxf((acc[i] + bias[ch + i] - rmean[ch + i]) * sc + beta[ch + i], 0.f);
        }
        uint4 o;
        o.x = pack2bf(r[0], r[1]); o.y = pack2bf(r[2], r[3]);
        o.z = pack2bf(r[4], r[5]); o.w = pack2bf(r[6], r[7]);
        outb[(size_t)row * 16 + c] = o;
    }
}

// ---------------- SpMM layer 2: aggregate + bias + pooled-sum (block-reduced atomics) ----------------
__global__ __launch_bounds__(256) void k_spmm_pool(
    const uint4* __restrict__ xw4, const int* __restrict__ perm, const int* __restrict__ offs,
    const int* __restrict__ deg, const float* __restrict__ dinv, const float* __restrict__ bias,
    const int* __restrict__ batch, float* __restrict__ psum, int* __restrict__ pcnt) {
    __shared__ float red[4][128];
    __shared__ int gid[4];
    SPMM_GATHER()
    if (g == 0) {
        uint4 v = xw4[(size_t)row * 16 + c];
        float sd = di * di;
        ACC8(sd, v)
        int ch = c * 8;
        #pragma unroll
        for (int i = 0; i < 8; ++i) red[w][ch + i] = acc[i] + bias[ch + i];
    }
    if (lane == 0) gid[w] = batch[row];
    __syncthreads();
    bool same = (gid[0] == gid[1]) && (gid[1] == gid[2]) && (gid[2] == gid[3]);
    int c0 = lane * 2;
    if (same) {
        if (w == 0) {
            float sx = red[0][c0] + red[1][c0] + red[2][c0] + red[3][c0];
            float sy = red[0][c0 + 1] + red[1][c0 + 1] + red[2][c0 + 1] + red[3][c0 + 1];
            unsafeAtomicAdd(&psum[gid[0] * CH + c0], sx);
            unsafeAtomicAdd(&psum[gid[0] * CH + c0 + 1], sy);
            if (lane == 0) atomicAdd(&pcnt[gid[0]], 4);
        }
    } else {
        unsafeAtomicAdd(&psum[gid[w] * CH + c0], red[w][c0]);
        unsafeAtomicAdd(&psum[gid[w] * CH + c0 + 1], red[w][c0 + 1]);
        if (lane == 0) atomicAdd(&pcnt[gid[w]], 1);
    }
}

// ---------------- head: pooled mean -> FC(relu) -> classifier ----------------
__global__ __launch_bounds__(128) void k_head(const float* __restrict__ psum, const int* __restrict__ pcnt,
                                              const float* __restrict__ fw1, const float* __restrict__ fb1,
                                              const float* __restrict__ cw, const float* __restrict__ cb,
                                              float* __restrict__ out) {
    __shared__ float fws[128 * 64];
    for (int i = threadIdx.x; i < 128 * 64; i += 128) fws[i] = fw1[i];
    __syncthreads();
    int g = threadIdx.x;
    float z[64];
    #pragma unroll
    for (int j = 0; j < 64; ++j) z[j] = fb1[j];
    float cnt = fmaxf((float)pcnt[g], 1.f);
    float inv = 1.f / cnt;
    for (int c = 0; c < 128; ++c) {
        float p = psum[g * CH + c] * inv;
        #pragma unroll
        for (int j = 0; j < 64; ++j) z[j] += p * fws[c * 64 + j];
    }
    float o0 = cb[0], o1 = cb[1];
    #pragma unroll
    for (int j = 0; j < 64; ++j) {
        float zz = fmaxf(z[j], 0.f);
        o0 += zz * cw[j * 2];
        o1 += zz * cw[j * 2 + 1];
    }
    out[g * 2] = o0;
    out[g * 2 + 1] = o1;
}

extern "C" void kernel_launch(void* const* d_in, const int* in_sizes, int n_in,
                              void* d_out, int out_size, void* d_ws, size_t ws_size,
                              hipStream_t stream) {
    const float* x     = (const float*)d_in[0];
    const int*   ei    = (const int*)d_in[1];
    const int*   batch = (const int*)d_in[2];
    const float* W1    = (const float*)d_in[3];
    const float* b1    = (const float*)d_in[4];
    const float* gamma = (const float*)d_in[5];
    const float* beta  = (const float*)d_in[6];
    const float* rmean = (const float*)d_in[7];
    const float* rvar  = (const float*)d_in[8];
    const float* W2    = (const float*)d_in[9];
    const float* b2    = (const float*)d_in[10];
    const float* fw1   = (const float*)d_in[11];
    const float* fb1   = (const float*)d_in[12];
    const float* cw    = (const float*)d_in[13];
    const float* cb    = (const float*)d_in[14];
    const int* srcp = ei;
    const int* dstp = ei + N_EDGES;

    char* w = (char*)d_ws;
    // zeroed region first
    int*   bcnt  = (int*)w;   w += 4096;
    float* psum  = (float*)w; w += 65536;
    int*   pcnt  = (int*)w;   w += 512;
    size_t zbytes = 4096 + 65536 + 512;
    // non-zeroed
    int*   deg   = (int*)w;   w += 400000;
    int*   offs  = (int*)w;   w += 400000;
    float* dinv  = (float*)w; w += 400000;
    int*   boffs = (int*)w;   w += 4096;
    int*   bcur  = (int*)w;   w += 4096;
    unsigned int* pairs = (unsigned int*)w; w += 12800000;
    int*   perm  = (int*)w;   w += 12800000;
    unsigned int* bufA = (unsigned int*)w; w += 25600000;  // bf16x2 [100k,64]
    unsigned int* bufB = (unsigned int*)w; w += 25600000;  // bf16x2 [100k,64]

    hipMemsetAsync(d_ws, 0, zbytes, stream);
    k_bhist<<<200, 256, 0, stream>>>(dstp, bcnt);
    k_bscan<<<1, 256, 0, stream>>>(bcnt, boffs, bcur);
    k_bin<<<(N_EDGES + EPB - 1) / EPB, 256, 0, stream>>>(srcp, dstp, bcur, pairs);
    k_bfill<<<NBUCK, 256, 0, stream>>>(pairs, boffs, offs, deg, dinv, perm);
    k_gemm<0><<<1563, 256, 0, stream>>>(x, W1, bufA, N_NODES);
    k_spmm_bn_relu<<<25000, 256, 0, stream>>>((const uint4*)bufA, perm, offs, deg, dinv, b1, gamma, beta, rmean, rvar, (uint4*)bufB);
    k_gemm<1><<<1563, 256, 0, stream>>>(bufB, W2, bufA, N_NODES);
    k_spmm_pool<<<25000, 256, 0, stream>>>((const uint4*)bufA, perm, offs, deg, dinv, b2, batch, psum, pcnt);
    k_head<<<1, 128, 0, stream>>>(psum, pcnt, fw1, fb1, cw, cb, (float*)d_out);
}

// Round 8
// 641.482 us; speedup vs baseline: 7.4443x; 1.0717x over previous
//
#include <hip/hip_runtime.h>
#include <hip/hip_bf16.h>

#define N_NODES 100000
#define N_EDGES 3200000
#define CH 128
#define NG 128
#define BN_EPS 1e-5f
#define NBUCK 1024   // bucket = dst >> 7 (128 nodes per bucket)
#define EPB 16384    // edges per k_bin block
#define NTILE 7      // src tile = src >> 14 (kept: zero-cost)

__device__ __forceinline__ float bflo(unsigned int u) { return __uint_as_float(u << 16); }
__device__ __forceinline__ float bfhi(unsigned int u) { return __uint_as_float(u & 0xffff0000u); }

__device__ __forceinline__ unsigned int packq(const float* v, float inv) {
    int q0 = __float2int_rn(v[0] * inv), q1 = __float2int_rn(v[1] * inv);
    int q2 = __float2int_rn(v[2] * inv), q3 = __float2int_rn(v[3] * inv);
    return (unsigned int)(q0 & 255) | ((unsigned int)(q1 & 255) << 8) |
           ((unsigned int)(q2 & 255) << 16) | ((unsigned int)(q3 & 255) << 24);
}

// ---------------- bucket histogram ----------------
__global__ __launch_bounds__(256) void k_bhist(const int* __restrict__ dst, int* __restrict__ bcnt) {
    __shared__ int lh[NBUCK];
    for (int i = threadIdx.x; i < NBUCK; i += 256) lh[i] = 0;
    __syncthreads();
    for (int e = blockIdx.x * 256 + threadIdx.x; e < N_EDGES; e += gridDim.x * 256)
        atomicAdd(&lh[dst[e] >> 7], 1);
    __syncthreads();
    for (int i = threadIdx.x; i < NBUCK; i += 256) {
        int v = lh[i];
        if (v) atomicAdd(&bcnt[i], v);
    }
}

// ---------------- bucket scan ----------------
__global__ __launch_bounds__(256) void k_bscan(const int* __restrict__ bcnt, int* __restrict__ boffs,
                                               int* __restrict__ bcur) {
    __shared__ int sm[256];
    int t = threadIdx.x;
    int4 v = *(const int4*)&bcnt[t * 4];
    int tsum = v.x + v.y + v.z + v.w;
    sm[t] = tsum;
    __syncthreads();
    for (int off = 1; off < 256; off <<= 1) {
        int val = sm[t];
        int add = (t >= off) ? sm[t - off] : 0;
        __syncthreads();
        sm[t] = val + add;
        __syncthreads();
    }
    int excl = sm[t] - tsum;
    int o0 = excl, o1 = excl + v.x, o2 = o1 + v.y, o3 = o2 + v.z;
    boffs[t * 4] = o0; boffs[t * 4 + 1] = o1; boffs[t * 4 + 2] = o2; boffs[t * 4 + 3] = o3;
    bcur[t * 4] = o0;  bcur[t * 4 + 1] = o1;  bcur[t * 4 + 2] = o2;  bcur[t * 4 + 3] = o3;
}

// ---------------- bin edges into per-bucket packed segments ----------------
__global__ __launch_bounds__(256) void k_bin(const int* __restrict__ src, const int* __restrict__ dst,
                                             int* __restrict__ bcur, unsigned int* __restrict__ pairs) {
    __shared__ int lhist[NBUCK];
    __shared__ int lbase[NBUCK];
    int t = threadIdx.x;
    for (int i = t; i < NBUCK; i += 256) lhist[i] = 0;
    __syncthreads();
    int base = blockIdx.x * EPB;
    int lim = min(base + EPB, N_EDGES);
    for (int e = base + t; e < lim; e += 256)
        atomicAdd(&lhist[dst[e] >> 7], 1);
    __syncthreads();
    for (int i = t; i < NBUCK; i += 256) {
        int h = lhist[i];
        lbase[i] = h ? atomicAdd(&bcur[i], h) : 0;
        lhist[i] = 0;
    }
    __syncthreads();
    for (int e = base + t; e < lim; e += 256) {
        int d = dst[e];
        int b = d >> 7;
        int r = atomicAdd(&lhist[b], 1);
        pairs[lbase[b] + r] = ((unsigned int)src[e] << 7) | ((unsigned int)d & 127u);
    }
}

// ---------------- per-bucket CSR fill (tile-sorted within row) + deg/offs/dinv ----------------
__global__ __launch_bounds__(256) void k_bfill(const unsigned int* __restrict__ pairs,
                                               const int* __restrict__ boffs,
                                               int* __restrict__ offs, int* __restrict__ deg,
                                               float* __restrict__ dinv, int* __restrict__ perm) {
    __shared__ int cnt[128 * 8];
    __shared__ int pos[128 * 8];
    __shared__ int lsc[128];
    int b = blockIdx.x, t = threadIdx.x;
    for (int i = t; i < 128 * 8; i += 256) cnt[i] = 0;
    __syncthreads();
    int p0 = boffs[b];
    int p1 = (b == NBUCK - 1) ? N_EDGES : boffs[b + 1];
    for (int p = p0 + t; p < p1; p += 256) {
        unsigned int e = pairs[p];
        atomicAdd(&cnt[(e & 127u) * 8 + ((e >> 7) >> 14)], 1);
    }
    __syncthreads();
    int mydeg = 0;
    if (t < 128) {
        #pragma unroll
        for (int k = 0; k < NTILE; ++k) mydeg += cnt[t * 8 + k];
        lsc[t] = mydeg;
    }
    __syncthreads();
    for (int off = 1; off < 128; off <<= 1) {
        int val = 0, add = 0;
        if (t < 128) { val = lsc[t]; add = (t >= off) ? lsc[t - off] : 0; }
        __syncthreads();
        if (t < 128) lsc[t] = val + add;
        __syncthreads();
    }
    if (t < 128) {
        int excl = lsc[t] - mydeg + p0;
        int node = (b << 7) + t;
        if (node < N_NODES) {
            offs[node] = excl;
            deg[node] = mydeg;
            dinv[node] = rsqrtf((float)(mydeg + 1));
        }
        int run = excl;
        #pragma unroll
        for (int k = 0; k < NTILE; ++k) {
            pos[t * 8 + k] = run;
            run += cnt[t * 8 + k];
            cnt[t * 8 + k] = 0;
        }
    }
    __syncthreads();
    for (int p = p0 + t; p < p1; p += 256) {
        unsigned int e = pairs[p];
        int local = (int)(e & 127u);
        unsigned int s = e >> 7;
        int tile = (int)(s >> 14);
        int r = atomicAdd(&cnt[local * 8 + tile], 1);
        perm[pos[local * 8 + tile] + r] = (int)s;
    }
}

// ---------------- GEMM: Yq_int8[nrows,128] = X @ W, with row-max quant epilogue ----------------
// MODE 0: X fp32. MODE 2: X int8 + per-row raw scale xsc.
// Output: int8 rows (uint2[16]/row) + spre[row] = (rowmax/127) * dinv[row].
template <int MODE>
__global__ __launch_bounds__(256) void k_gemm(const void* __restrict__ Xv, const float* __restrict__ xsc,
                                              const float* __restrict__ W, const float* __restrict__ dinvp,
                                              uint2* __restrict__ Yq, float* __restrict__ ospre, int nrows) {
    __shared__ float xsT[128 * 64];  // [k][r]
    int row0 = blockIdx.x * 64;
    int t = threadIdx.x;
    {
        int r = t >> 2, q = t & 3;
        int grow = row0 + r;
        bool ok = grow < nrows;
        if (MODE == 2) {
            float sc = ok ? xsc[grow] : 0.f;
            const uint2* srcp = (const uint2*)Xv + (size_t)grow * 16 + q * 4;
            #pragma unroll
            for (int i = 0; i < 4; ++i) {
                uint2 u = ok ? srcp[i] : make_uint2(0, 0);
                int a = (int)u.x, bb = (int)u.y;
                int c = q * 32 + i * 8;
                xsT[(c + 0) * 64 + r] = sc * (float)((a << 24) >> 24);
                xsT[(c + 1) * 64 + r] = sc * (float)((a << 16) >> 24);
                xsT[(c + 2) * 64 + r] = sc * (float)((a << 8) >> 24);
                xsT[(c + 3) * 64 + r] = sc * (float)(a >> 24);
                xsT[(c + 4) * 64 + r] = sc * (float)((bb << 24) >> 24);
                xsT[(c + 5) * 64 + r] = sc * (float)((bb << 16) >> 24);
                xsT[(c + 6) * 64 + r] = sc * (float)((bb << 8) >> 24);
                xsT[(c + 7) * 64 + r] = sc * (float)(bb >> 24);
            }
        } else {
            const float4* srcp = (const float4*)((const float*)Xv + (size_t)grow * CH + q * 32);
            #pragma unroll
            for (int i = 0; i < 8; ++i) {
                float4 v = ok ? srcp[i] : make_float4(0.f, 0.f, 0.f, 0.f);
                int c = q * 32 + i * 4;
                xsT[(c + 0) * 64 + r] = v.x;
                xsT[(c + 1) * 64 + r] = v.y;
                xsT[(c + 2) * 64 + r] = v.z;
                xsT[(c + 3) * 64 + r] = v.w;
            }
        }
    }
    __syncthreads();
    int tx = t & 15, ty = t >> 4;
    float acc[4][8];
    #pragma unroll
    for (int i = 0; i < 4; ++i)
        #pragma unroll
        for (int j = 0; j < 8; ++j) acc[i][j] = 0.f;

    const float4* xs4 = (const float4*)xsT;
    #pragma unroll 4
    for (int k = 0; k < 128; ++k) {
        float4 a = xs4[k * 16 + ty];
        float4 w0 = *(const float4*)&W[k * CH + tx * 8];
        float4 w1 = *(const float4*)&W[k * CH + tx * 8 + 4];
        float av[4] = {a.x, a.y, a.z, a.w};
        float wv[8] = {w0.x, w0.y, w0.z, w0.w, w1.x, w1.y, w1.z, w1.w};
        #pragma unroll
        for (int i = 0; i < 4; ++i)
            #pragma unroll
            for (int j = 0; j < 8; ++j) acc[i][j] += av[i] * wv[j];
    }
    #pragma unroll
    for (int i = 0; i < 4; ++i) {
        int grow = row0 + ty * 4 + i;
        float m = 0.f;
        #pragma unroll
        for (int j = 0; j < 8; ++j) m = fmaxf(m, fabsf(acc[i][j]));
        #pragma unroll
        for (int off = 1; off < 16; off <<= 1) m = fmaxf(m, __shfl_xor(m, off, 64));
        float inv = (m > 0.f) ? 127.0f / m : 0.f;
        if (grow < nrows) {
            uint2 pk;
            pk.x = packq(&acc[i][0], inv);
            pk.y = packq(&acc[i][4], inv);
            Yq[(size_t)grow * 16 + tx] = pk;
            if (tx == 0) ospre[grow] = (m * (1.0f / 127.0f)) * dinvp[grow];
        }
    }
}

// ---------------- SpMM gather core: 4 edge-slots x 16 lanes, int8 rows (uint2/lane) ----------------
#define ACCI8(f, v)                                                                    \
    { int _a = (int)v.x, _b = (int)v.y;                                                \
      acc[0] += f * (float)((_a << 24) >> 24);                                         \
      acc[1] += f * (float)((_a << 16) >> 24);                                         \
      acc[2] += f * (float)((_a << 8) >> 24);                                          \
      acc[3] += f * (float)(_a >> 24);                                                 \
      acc[4] += f * (float)((_b << 24) >> 24);                                         \
      acc[5] += f * (float)((_b << 16) >> 24);                                         \
      acc[6] += f * (float)((_b << 8) >> 24);                                          \
      acc[7] += f * (float)(_b >> 24); }

#define SPMM_GATHER()                                                                  \
    int w = threadIdx.x >> 6;                                                          \
    int row = __builtin_amdgcn_readfirstlane(blockIdx.x * 4 + w);                      \
    int lane = threadIdx.x & 63;                                                       \
    int g = lane >> 4, c = lane & 15;                                                  \
    float di = dinv[row];                                                              \
    float acc[8];                                                                      \
    _Pragma("unroll") for (int i = 0; i < 8; ++i) acc[i] = 0.f;                        \
    int beg = offs[row], end = beg + deg[row];                                         \
    int j = beg + g;                                                                   \
    for (; j + 12 < end; j += 16) {                                                    \
        int s0 = perm[j], s1 = perm[j + 4], s2 = perm[j + 8], s3 = perm[j + 12];       \
        float f0 = spre[s0], f1 = spre[s1], f2 = spre[s2], f3 = spre[s3];              \
        uint2 v0 = xq[(size_t)s0 * 16 + c];                                            \
        uint2 v1 = xq[(size_t)s1 * 16 + c];                                            \
        uint2 v2 = xq[(size_t)s2 * 16 + c];                                            \
        uint2 v3 = xq[(size_t)s3 * 16 + c];                                            \
        f0 *= di; f1 *= di; f2 *= di; f3 *= di;                                        \
        ACCI8(f0, v0) ACCI8(f1, v1) ACCI8(f2, v2) ACCI8(f3, v3)                        \
    }                                                                                  \
    for (; j + 4 < end; j += 8) {                                                      \
        int s0 = perm[j], s1 = perm[j + 4];                                            \
        float f0 = di * spre[s0], f1 = di * spre[s1];                                  \
        uint2 v0 = xq[(size_t)s0 * 16 + c];                                            \
        uint2 v1 = xq[(size_t)s1 * 16 + c];                                            \
        ACCI8(f0, v0) ACCI8(f1, v1)                                                    \
    }                                                                                  \
    if (j < end) {                                                                     \
        int s = perm[j];                                                               \
        float f = di * spre[s];                                                        \
        uint2 v = xq[(size_t)s * 16 + c];                                              \
        ACCI8(f, v)                                                                    \
    }                                                                                  \
    _Pragma("unroll") for (int i = 0; i < 8; ++i) {                                    \
        acc[i] += __shfl_xor(acc[i], 16, 64);                                          \
        acc[i] += __shfl_xor(acc[i], 32, 64);                                          \
    }

// ---------------- SpMM layer 1: aggregate + bias + BN + ReLU -> int8 + raw scale ----------------
__global__ __launch_bounds__(256) void k_spmm_bn_relu(
    const uint2* __restrict__ xq, const int* __restrict__ perm, const int* __restrict__ offs,
    const int* __restrict__ deg, const float* __restrict__ dinv, const float* __restrict__ spre,
    const float* __restrict__ bias, const float* __restrict__ gamma, const float* __restrict__ beta,
    const float* __restrict__ rmean, const float* __restrict__ rvar,
    uint2* __restrict__ outq, float* __restrict__ osraw) {
    SPMM_GATHER()
    if (g == 0) {
        uint2 v = xq[(size_t)row * 16 + c];
        float fs = di * spre[row];
        ACCI8(fs, v)
        int ch = c * 8;
        float r[8];
        #pragma unroll
        for (int i = 0; i < 8; ++i) {
            float sc = gamma[ch + i] * rsqrtf(rvar[ch + i] + BN_EPS);
            r[i] = fmaxf((acc[i] + bias[ch + i] - rmean[ch + i]) * sc + beta[ch + i], 0.f);
        }
        float m = 0.f;
        #pragma unroll
        for (int i = 0; i < 8; ++i) m = fmaxf(m, r[i]);
        #pragma unroll
        for (int off = 1; off < 16; off <<= 1) m = fmaxf(m, __shfl_xor(m, off, 64));
        float inv = (m > 0.f) ? 127.0f / m : 0.f;
        uint2 pk;
        pk.x = packq(&r[0], inv);
        pk.y = packq(&r[4], inv);
        outq[(size_t)row * 16 + c] = pk;
        if (c == 0) osraw[row] = m * (1.0f / 127.0f);
    }
}

// ---------------- SpMM layer 2: aggregate + bias + pooled-sum (block-reduced atomics) ----------------
__global__ __launch_bounds__(256) void k_spmm_pool(
    const uint2* __restrict__ xq, const int* __restrict__ perm, const int* __restrict__ offs,
    const int* __restrict__ deg, const float* __restrict__ dinv, const float* __restrict__ spre,
    const float* __restrict__ bias, const int* __restrict__ batch,
    float* __restrict__ psum, int* __restrict__ pcnt) {
    __shared__ float red[4][128];
    __shared__ int gid[4];
    SPMM_GATHER()
    if (g == 0) {
        uint2 v = xq[(size_t)row * 16 + c];
        float fs = di * spre[row];
        ACCI8(fs, v)
        int ch = c * 8;
        #pragma unroll
        for (int i = 0; i < 8; ++i) red[w][ch + i] = acc[i] + bias[ch + i];
    }
    if (lane == 0) gid[w] = batch[row];
    __syncthreads();
    bool same = (gid[0] == gid[1]) && (gid[1] == gid[2]) && (gid[2] == gid[3]);
    int c0 = lane * 2;
    if (same) {
        if (w == 0) {
            float sx = red[0][c0] + red[1][c0] + red[2][c0] + red[3][c0];
            float sy = red[0][c0 + 1] + red[1][c0 + 1] + red[2][c0 + 1] + red[3][c0 + 1];
            unsafeAtomicAdd(&psum[gid[0] * CH + c0], sx);
            unsafeAtomicAdd(&psum[gid[0] * CH + c0 + 1], sy);
            if (lane == 0) atomicAdd(&pcnt[gid[0]], 4);
        }
    } else {
        unsafeAtomicAdd(&psum[gid[w] * CH + c0], red[w][c0]);
        unsafeAtomicAdd(&psum[gid[w] * CH + c0 + 1], red[w][c0 + 1]);
        if (lane == 0) atomicAdd(&pcnt[gid[w]], 1);
    }
}

// ---------------- head ----------------
__global__ __launch_bounds__(128) void k_head(const float* __restrict__ psum, const int* __restrict__ pcnt,
                                              const float* __restrict__ fw1, const float* __restrict__ fb1,
                                              const float* __restrict__ cw, const float* __restrict__ cb,
                                              float* __restrict__ out) {
    __shared__ float fws[128 * 64];
    for (int i = threadIdx.x; i < 128 * 64; i += 128) fws[i] = fw1[i];
    __syncthreads();
    int g = threadIdx.x;
    float z[64];
    #pragma unroll
    for (int j = 0; j < 64; ++j) z[j] = fb1[j];
    float cnt = fmaxf((float)pcnt[g], 1.f);
    float inv = 1.f / cnt;
    for (int c = 0; c < 128; ++c) {
        float p = psum[g * CH + c] * inv;
        #pragma unroll
        for (int j = 0; j < 64; ++j) z[j] += p * fws[c * 64 + j];
    }
    float o0 = cb[0], o1 = cb[1];
    #pragma unroll
    for (int j = 0; j < 64; ++j) {
        float zz = fmaxf(z[j], 0.f);
        o0 += zz * cw[j * 2];
        o1 += zz * cw[j * 2 + 1];
    }
    out[g * 2] = o0;
    out[g * 2 + 1] = o1;
}

extern "C" void kernel_launch(void* const* d_in, const int* in_sizes, int n_in,
                              void* d_out, int out_size, void* d_ws, size_t ws_size,
                              hipStream_t stream) {
    const float* x     = (const float*)d_in[0];
    const int*   ei    = (const int*)d_in[1];
    const int*   batch = (const int*)d_in[2];
    const float* W1    = (const float*)d_in[3];
    const float* b1    = (const float*)d_in[4];
    const float* gamma = (const float*)d_in[5];
    const float* beta  = (const float*)d_in[6];
    const float* rmean = (const float*)d_in[7];
    const float* rvar  = (const float*)d_in[8];
    const float* W2    = (const float*)d_in[9];
    const float* b2    = (const float*)d_in[10];
    const float* fw1   = (const float*)d_in[11];
    const float* fb1   = (const float*)d_in[12];
    const float* cw    = (const float*)d_in[13];
    const float* cb    = (const float*)d_in[14];
    const int* srcp = ei;
    const int* dstp = ei + N_EDGES;

    char* w = (char*)d_ws;
    // zeroed region first
    int*   bcnt  = (int*)w;   w += 4096;
    float* psum  = (float*)w; w += 65536;
    int*   pcnt  = (int*)w;   w += 512;
    size_t zbytes = 4096 + 65536 + 512;
    // non-zeroed
    int*   deg   = (int*)w;   w += 400000;
    int*   offs  = (int*)w;   w += 400000;
    float* dinv  = (float*)w; w += 400000;
    float* spreA = (float*)w; w += 400000;
    float* srawB = (float*)w; w += 400000;
    float* spreC = (float*)w; w += 400000;
    int*   boffs = (int*)w;   w += 4096;
    int*   bcur  = (int*)w;   w += 4096;
    unsigned int* pairs = (unsigned int*)w; w += 12800000;
    int*   perm  = (int*)w;   w += 12800000;
    uint2* bufA  = (uint2*)w; w += 12800000;  // int8 [100k,128]
    uint2* bufB  = (uint2*)w; w += 12800000;  // int8 [100k,128]
    uint2* bufC  = (uint2*)w; w += 12800000;  // int8 [100k,128]

    hipMemsetAsync(d_ws, 0, zbytes, stream);
    k_bhist<<<200, 256, 0, stream>>>(dstp, bcnt);
    k_bscan<<<1, 256, 0, stream>>>(bcnt, boffs, bcur);
    k_bin<<<(N_EDGES + EPB - 1) / EPB, 256, 0, stream>>>(srcp, dstp, bcur, pairs);
    k_bfill<<<NBUCK, 256, 0, stream>>>(pairs, boffs, offs, deg, dinv, perm);
    k_gemm<0><<<1563, 256, 0, stream>>>(x, nullptr, W1, dinv, bufA, spreA, N_NODES);
    k_spmm_bn_relu<<<25000, 256, 0, stream>>>(bufA, perm, offs, deg, dinv, spreA,
                                              b1, gamma, beta, rmean, rvar, bufB, srawB);
    k_gemm<2><<<1563, 256, 0, stream>>>(bufB, srawB, W2, dinv, bufC, spreC, N_NODES);
    k_spmm_pool<<<25000, 256, 0, stream>>>(bufC, perm, offs, deg, dinv, spreC, b2, batch, psum, pcnt);
    k_head<<<1, 128, 0, stream>>>(psum, pcnt, fw1, fb1, cw, cb, (float*)d_out);
}